// Round 6
// baseline (875.012 us; speedup 1.0000x reference)
//
#include <hip/hip_runtime.h>
#include <math.h>

#define NEG_SLOPE   0.2f
#define CONSUME_R   0.1f     // RADIUS*2
#define ACCEL_SCALE 0.01f
#define MAX_VEL     0.1f

#define NBUCK  128
#define TPB    256
#define EPT    16
#define EPB    (TPB*EPT)     // 4096 edges per slice
#define MAXNPB 1600
#define MAXSPG 800
#define GSPLIT 4

typedef float    v2f __attribute__((ext_vector_type(2)));
typedef unsigned v2u __attribute__((ext_vector_type(2)));
typedef unsigned v4u __attribute__((ext_vector_type(4)));

__device__ __forceinline__ unsigned bucket_of(unsigned v, unsigned npb, float inv_npb,
                                              unsigned* loc)
{
    unsigned b = (unsigned)((float)v * inv_npb);
    unsigned lo = b * npb;
    if (v < lo)            { --b; lo -= npb; }
    else if (v >= lo + npb){ ++b; lo += npb; }
    *loc = v - lo;
    return b;
}

// ---------------------------------------------------------------------------
// k_pre: npack[i] = {h0|h1, h2|h3, h4, aS} (h bf16), aD[i] fp32
// ---------------------------------------------------------------------------
__global__ __launch_bounds__(256) void k_pre(
    const float* __restrict__ x, const float* __restrict__ W,
    const float* __restrict__ att_src, const float* __restrict__ att_dst,
    uint4* __restrict__ npack, float* __restrict__ aD, int n)
{
    int i = blockIdx.x * 256 + threadIdx.x;
    if (i >= n) return;
    float xr[5];
#pragma unroll
    for (int k = 0; k < 5; ++k) xr[k] = x[(size_t)i * 5 + k];
    float hs[5];
#pragma unroll
    for (int c = 0; c < 5; ++c) {
        float s = 0.f;
#pragma unroll
        for (int k = 0; k < 5; ++k) s += xr[k] * W[k * 5 + c];
        hs[c] = s;
    }
    float a_s = 0.f, a_d = 0.f;
#pragma unroll
    for (int c = 0; c < 5; ++c) { a_s += hs[c] * att_src[c]; a_d += hs[c] * att_dst[c]; }
    aD[i] = a_d;
    unsigned b[5];
#pragma unroll
    for (int c = 0; c < 5; ++c) {   // round-to-nearest-even bf16
        unsigned u = __float_as_uint(hs[c]);
        b[c] = (u + 0x7FFFu + ((u >> 16) & 1u)) >> 16;
    }
    npack[i] = make_uint4(b[0] | (b[1] << 16), b[2] | (b[3] << 16), b[4],
                          __float_as_uint(a_s));
}

// ---------------------------------------------------------------------------
// k_hist: per-slice dst-bucket histogram. Reads only the dst row (51 MB).
// hist layout [bucket][slice] (row stride NB).
// ---------------------------------------------------------------------------
__global__ __launch_bounds__(TPB) void k_hist(
    const int* __restrict__ dst, int* __restrict__ hist,
    int NB, int nE, unsigned npb, float inv_npb)
{
    __shared__ int hd[NBUCK];
    int t = threadIdx.x, blk = blockIdx.x;
    if (t < NBUCK) hd[t] = 0;
    __syncthreads();
    int base = blk * EPB;
#pragma unroll 4
    for (int k = 0; k < EPT; ++k) {
        int e = base + k * TPB + t;
        if (e < nE) {
            unsigned d = (unsigned)__builtin_nontemporal_load(dst + e);
            unsigned loc;
            unsigned bd = bucket_of(d, npb, inv_npb, &loc);
            atomicAdd(&hd[bd], 1);
        }
    }
    __syncthreads();
    if (t < NBUCK) hist[(size_t)t * NB + blk] = hd[t];
}

// ---------------------------------------------------------------------------
// k_scanA: in-place exclusive scan of each bucket row (one block per bucket).
// rowtot[b] = row sum.
// ---------------------------------------------------------------------------
__global__ __launch_bounds__(256) void k_scanA(
    int* __restrict__ hist, int* __restrict__ rowtot, int NB)
{
    int b = blockIdx.x, t = threadIdx.x;
    int* row = hist + (size_t)b * NB;
    __shared__ int ws[4];
    __shared__ int carry;
    if (t == 0) carry = 0;
    __syncthreads();
    for (int base = 0; base < NB; base += 256) {
        int i = base + t;
        int v = (i < NB) ? row[i] : 0;
        int xv = v;
#pragma unroll
        for (int off = 1; off < 64; off <<= 1) {
            int y = __shfl_up(xv, off);
            if ((t & 63) >= off) xv += y;
        }
        if ((t & 63) == 63) ws[t >> 6] = xv;
        __syncthreads();
        int add = 0;
        for (int w = 0; w < (t >> 6); ++w) add += ws[w];
        int total = ws[0] + ws[1] + ws[2] + ws[3];
        if (i < NB) row[i] = carry + xv + add - v;
        __syncthreads();
        if (t == 0) carry += total;
        __syncthreads();
    }
    if (t == 0) rowtot[b] = carry;
}

// k_scanB: exclusive scan of rowtot -> bbase[0..NBUCK], one block of 128
__global__ __launch_bounds__(128) void k_scanB(
    const int* __restrict__ rowtot, int* __restrict__ bbase)
{
    __shared__ int w0;
    int t = threadIdx.x;
    int v = rowtot[t];
    int xv = v;
#pragma unroll
    for (int off = 1; off < 64; off <<= 1) {
        int y = __shfl_up(xv, off);
        if ((t & 63) >= off) xv += y;
    }
    if (t == 63) w0 = xv;
    __syncthreads();
    int excl = xv - v + ((t >= 64) ? w0 : 0);
    bbase[t] = excl;
    if (t == 127) bbase[128] = excl + v;
}

// ---------------------------------------------------------------------------
// k_scatter<CARRY_H>: one pass over edges. payD written bucket-contiguous
// globally (base = bbase[bd] + hist[bd][slice], rank via LDS counter).
// CARRY_H: 16B rec {h0|h1, h2|h3, h4|dloc<<16, partial}; else 8B
// {src|dloc<<18, partial}. payS slice-local (LDS-staged, contiguous dump).
// ---------------------------------------------------------------------------
template <bool CARRY_H>
__global__ __launch_bounds__(TPB) void k_scatter(
    const int* __restrict__ ei, const float* __restrict__ ea,
    const uint4* __restrict__ npack,
    const float* __restrict__ We, const float* __restrict__ att_edge,
    const int* __restrict__ hist, const int* __restrict__ bbase,
    void* __restrict__ payD, unsigned short* __restrict__ payS,
    int* __restrict__ dirS, int NB, int nE, unsigned npb, float inv_npb)
{
    __shared__ int cD[NBUCK], cS[NBUCK], baseS[NBUCK], dirGl[NBUCK];
    __shared__ unsigned short paySL[EPB];
    __shared__ int wsS[2];
    int t = threadIdx.x, blk = blockIdx.x;
    if (t < NBUCK) {
        cD[t] = 0; cS[t] = 0;
        dirGl[t] = bbase[t] + hist[(size_t)t * NB + blk];
    }
    __syncthreads();

    float v0 = 0.f, v1 = 0.f;
#pragma unroll
    for (int c = 0; c < 5; ++c) { v0 += We[c] * att_edge[c]; v1 += We[5 + c] * att_edge[c]; }

    int base = blk * EPB;
    unsigned meta[EPT], rw0[EPT], rw1[EPT], rw2[EPT];
    float rp[EPT];

    // pass A: load streams, gather npack[s], count payS buckets
#pragma unroll
    for (int k = 0; k < EPT; ++k) {
        int e = base + k * TPB + t;
        meta[k] = 0xFFFFFFFFu;
        if (e < nE) {
            unsigned s = (unsigned)__builtin_nontemporal_load(ei + e);
            unsigned d = (unsigned)__builtin_nontemporal_load(ei + nE + e);
            v2f at = __builtin_nontemporal_load((const v2f*)ea + e);
            unsigned dloc, sloc;
            unsigned bd = bucket_of(d, npb, inv_npb, &dloc);
            unsigned bs = bucket_of(s, npb, inv_npb, &sloc);
            uint4 hp = npack[s];
            rp[k] = __uint_as_float(hp.w) + at.x * v0 + at.y * v1;
            if (CARRY_H) {
                rw0[k] = hp.x; rw1[k] = hp.y;
                rw2[k] = (hp.z & 0xFFFFu) | (dloc << 16);
            } else {
                rw0[k] = s | (dloc << 18);
            }
            bool close = at.x < CONSUME_R;
            bool cell  = (at.y == 1.0f);
            unsigned srec = sloc | (close ? 0x800u : 0u) | (cell ? 0x1000u : 0u);
            meta[k] = bd | (bs << 8) | (srec << 16);
            if (close || cell) atomicAdd(&cS[bs], 1);
        }
    }
    __syncthreads();

    // slice-local exclusive scan of cS (128 entries, 2 waves)
    int vS = (t < NBUCK) ? cS[t] : 0;
    int xS = vS;
#pragma unroll
    for (int off = 1; off < 64; off <<= 1) {
        int y = __shfl_up(xS, off);
        if ((t & 63) >= off) xS += y;
    }
    if (t == 63) wsS[0] = xS;
    if (t == 127) wsS[1] = xS;
    __syncthreads();
    if (t < NBUCK) {
        int excl = xS - vS + ((t >= 64) ? wsS[0] : 0);
        baseS[t] = excl;
        dirS[(size_t)t * NB + blk] = excl;
        cS[t] = 0;
    }
    if (t == 0) dirS[(size_t)NBUCK * NB + blk] = wsS[0] + wsS[1];
    __syncthreads();

    // pass B: rank + write payD to global bucket-contiguous runs; payS to LDS
#pragma unroll
    for (int k = 0; k < EPT; ++k) {
        if (meta[k] != 0xFFFFFFFFu) {
            unsigned bd = meta[k] & 0xFFu, bs = (meta[k] >> 8) & 0xFFu;
            unsigned srec = meta[k] >> 16;
            int r = atomicAdd(&cD[bd], 1);
            if (CARRY_H)
                ((uint4*)payD)[dirGl[bd] + r] =
                    make_uint4(rw0[k], rw1[k], rw2[k], __float_as_uint(rp[k]));
            else
                ((uint2*)payD)[dirGl[bd] + r] =
                    make_uint2(rw0[k], __float_as_uint(rp[k]));
            if (srec & 0x1800u) {
                int r2 = atomicAdd(&cS[bs], 1);
                paySL[baseS[bs] + r2] = (unsigned short)srec;
            }
        }
    }
    __syncthreads();

    // dump payS slice contiguously (8KB)
    unsigned* pgs = (unsigned*)(payS + (size_t)blk * EPB);
    const unsigned* pls = (const unsigned*)paySL;
#pragma unroll
    for (int j = 0; j < EPB / 2 / TPB; ++j) pgs[j * TPB + t] = pls[j * TPB + t];
}

// ---------------------------------------------------------------------------
// k_accum<CARRY_H>: block (b,g) streams its contiguous payD span; LDS
// accumulate; payS runs via 16-lane groups; write partials.
// ---------------------------------------------------------------------------
template <bool CARRY_H>
__global__ __launch_bounds__(1024) void k_accum(
    const void* __restrict__ payD, const unsigned short* __restrict__ payS,
    const int* __restrict__ bbase, const int* __restrict__ dirS,
    const uint4* __restrict__ npack, const float* __restrict__ aD,
    float* __restrict__ accp, int* __restrict__ cntp,
    int NB, int G, int SPG, int n, int npb)
{
    __shared__ float accf[MAXNPB * 6];
    __shared__ int   cnts[MAXNPB];
    __shared__ float aDl[MAXNPB];
    __shared__ int   stS[MAXSPG], enS[MAXSPG];

    int b = blockIdx.x & (NBUCK - 1);
    int g = blockIdx.x >> 7;
    int t = threadIdx.x;
    int first = b * npb;
    int nodes = n - first; if (nodes > npb) nodes = npb; if (nodes < 0) nodes = 0;

    for (int j = t; j < npb * 6; j += 1024) accf[j] = 0.f;
    for (int j = t; j < npb;     j += 1024) cnts[j] = 0;
    for (int j = t; j < nodes;   j += 1024) aDl[j] = aD[first + j];
    int s0 = g * SPG, s1 = min(NB, s0 + SPG), ns = s1 - s0;
    for (int j = t; j < ns; j += 1024) {
        stS[j] = dirS[(size_t)b * NB + s0 + j];
        enS[j] = dirS[(size_t)(b + 1) * NB + s0 + j];
    }
    __syncthreads();

    // contiguous payD span for (b,g)
    int lo = bbase[b], hi = bbase[b + 1];
    int len = hi - lo;
    int ss = lo + (int)((long long)len * g / G);
    int ee = lo + (int)((long long)len * (g + 1) / G);
    for (int idx = ss + t; idx < ee; idx += 1024) {
        float h0, h1, h2, h3, h4, z;
        unsigned dloc;
        if (CARRY_H) {
            v4u rec = __builtin_nontemporal_load((const v4u*)payD + idx);
            h0 = __uint_as_float(rec.x << 16);
            h1 = __uint_as_float(rec.x & 0xFFFF0000u);
            h2 = __uint_as_float(rec.y << 16);
            h3 = __uint_as_float(rec.y & 0xFFFF0000u);
            h4 = __uint_as_float(rec.z << 16);
            dloc = rec.z >> 16;
            z = __uint_as_float(rec.w);
        } else {
            v2u rec = __builtin_nontemporal_load((const v2u*)payD + idx);
            unsigned src = rec.x & 0x3FFFFu;
            dloc = rec.x >> 18;
            uint4 hp = npack[src];
            h0 = __uint_as_float(hp.x << 16);
            h1 = __uint_as_float(hp.x & 0xFFFF0000u);
            h2 = __uint_as_float(hp.y << 16);
            h3 = __uint_as_float(hp.y & 0xFFFF0000u);
            h4 = __uint_as_float(hp.z << 16);
            z = __uint_as_float(rec.y);
        }
        z += aDl[dloc];
        float l = z > 0.f ? z : NEG_SLOPE * z;
        float ev = __expf(l);
        float* a = &accf[dloc * 6];
        atomicAdd(a + 0, ev * h0);
        atomicAdd(a + 1, ev * h1);
        atomicAdd(a + 2, ev * h2);
        atomicAdd(a + 3, ev * h3);
        atomicAdd(a + 4, ev * h4);
        atomicAdd(a + 5, ev);
    }

    // payS runs (slice-local layout)
    int q = t >> 4, l16 = t & 15;
    for (int i = q; i < ns; i += 64) {
        size_t sbase = (size_t)(s0 + i) * EPB;
        int st = stS[i], en = enS[i];
        for (int j = st + l16; j < en; j += 16) {
            unsigned srec = __builtin_nontemporal_load(payS + sbase + j);
            int add = (int)((srec >> 11) & 1u) | (int)(((srec >> 12) & 1u) << 16);
            atomicAdd(&cnts[srec & 0x7FFu], add);
        }
    }
    __syncthreads();

    size_t P = (size_t)(b * G + g) * npb;
    for (int j = t; j < nodes * 6; j += 1024) accp[P * 6 + j] = accf[j];
    for (int j = t; j < nodes;     j += 1024) cntp[P + j] = cnts[j];
}

// ---------------------------------------------------------------------------
// k_final: merge G partials, MLP, physics, scalar reduction
// ---------------------------------------------------------------------------
__global__ __launch_bounds__(256) void k_final(
    const float* __restrict__ x, const float* __restrict__ accp,
    const int* __restrict__ cntp, int G, int npb, float inv_npb,
    const float* __restrict__ gat_bias, const float* __restrict__ W1,
    const float* __restrict__ b1, const float* __restrict__ W2,
    const float* __restrict__ b2,
    float* __restrict__ out, float* __restrict__ scal, int n)
{
    int i = blockIdx.x * 256 + threadIdx.x;
    float part[5] = {0.f, 0.f, 0.f, 0.f, 0.f};

    if (i < n) {
        unsigned loc;
        unsigned b = bucket_of((unsigned)i, (unsigned)npb, inv_npb, &loc);
        float a[6] = {0.f, 0.f, 0.f, 0.f, 0.f, 0.f};
        int c = 0;
        for (int g = 0; g < G; ++g) {
            size_t P = (size_t)(b * G + g) * npb + loc;
            const float* p = accp + P * 6;
#pragma unroll
            for (int k = 0; k < 6; ++k) a[k] += p[k];
            c += cntp[P];
        }
        float inv = 1.0f / fmaxf(a[5], 1e-16f);
        float h[5];
#pragma unroll
        for (int k = 0; k < 5; ++k) h[k] = a[k] * inv + gat_bias[k];
        float tt[5];
#pragma unroll
        for (int cc = 0; cc < 5; ++cc) {
            float s = b1[cc];
#pragma unroll
            for (int k = 0; k < 5; ++k) s += h[k] * W1[k * 5 + cc];
            tt[cc] = fmaxf(s, 0.f);
        }
        float u0 = b2[0], u1 = b2[1];
#pragma unroll
        for (int k = 0; k < 5; ++k) { u0 += tt[k] * W2[k * 2]; u1 += tt[k] * W2[k * 2 + 1]; }
        u0 = fmaxf(u0, 0.f) * 2.f - 1.f;
        u1 = fmaxf(u1, 0.f) * 2.f - 1.f;

        float px = x[(size_t)i * 5],     py = x[(size_t)i * 5 + 1];
        float vx = x[(size_t)i * 5 + 2], vy = x[(size_t)i * 5 + 3];
        float ty = x[(size_t)i * 5 + 4];
        float mask = (ty == 1.0f) ? 1.0f : 0.0f;
        float nvx = fminf(fmaxf(vx + u0 * ACCEL_SCALE * mask, -MAX_VEL), MAX_VEL);
        float nvy = fminf(fmaxf(vy + u1 * ACCEL_SCALE * mask, -MAX_VEL), MAX_VEL);
        float npx = px + nvx, npy = py + nvy;

        out[(size_t)i * 5]     = npx;
        out[(size_t)i * 5 + 1] = npy;
        out[(size_t)i * 5 + 2] = nvx;
        out[(size_t)i * 5 + 3] = nvy;
        out[(size_t)i * 5 + 4] = ty;

        part[0] = fabsf(nvx);
        part[1] = fabsf(nvy);
        float bc = 0.f;
        if (fabsf(npx) > 1.0f) bc += logf(fabsf(npx) + 1e-6f);
        if (fabsf(npy) > 1.0f) bc += logf(fabsf(npy) + 1e-6f);
        part[2] = bc;
        part[3] = (ty == 0.0f && (c & 0xffff) >= 3) ? 1.f : 0.f;
        part[4] = (ty == 1.0f && (c >> 16) < 1) ? 1.f : 0.f;
    }

    __shared__ float sm[4][5];
#pragma unroll
    for (int q = 0; q < 5; ++q)
#pragma unroll
        for (int off = 32; off > 0; off >>= 1)
            part[q] += __shfl_down(part[q], off);
    int lane = threadIdx.x & 63, wid = threadIdx.x >> 6;
    if (lane == 0)
#pragma unroll
        for (int q = 0; q < 5; ++q) sm[wid][q] = part[q];
    __syncthreads();
    if (threadIdx.x == 0) {
#pragma unroll
        for (int q = 0; q < 5; ++q)
            unsafeAtomicAdd(scal + q, sm[0][q] + sm[1][q] + sm[2][q] + sm[3][q]);
    }
}

__global__ void k_tail(const float* __restrict__ scal, float* __restrict__ out, int n)
{
    if (threadIdx.x == 0 && blockIdx.x == 0) {
        size_t base = (size_t)n * 5;
        float invn = 1.0f / (float)n;
        out[base + 0] = scal[0] * invn;
        out[base + 1] = scal[1] * invn;
        out[base + 2] = scal[2];
        out[base + 3] = scal[3];
        out[base + 4] = scal[4];
    }
}

// ------------------- fallback (round-1 atomic path) ------------------------
__global__ __launch_bounds__(256) void k_node_pre_fb(
    const float* __restrict__ x, const float* __restrict__ W,
    const float* __restrict__ att_src, const float* __restrict__ att_dst,
    float* __restrict__ npack, int n)
{
    int i = blockIdx.x * 256 + threadIdx.x;
    if (i >= n) return;
    float xr[5];
#pragma unroll
    for (int k = 0; k < 5; ++k) xr[k] = x[(size_t)i * 5 + k];
    float hs[5];
#pragma unroll
    for (int c = 0; c < 5; ++c) {
        float s = 0.f;
#pragma unroll
        for (int k = 0; k < 5; ++k) s += xr[k] * W[k * 5 + c];
        hs[c] = s;
    }
    float a_s = 0.f, a_d = 0.f;
#pragma unroll
    for (int c = 0; c < 5; ++c) { a_s += hs[c] * att_src[c]; a_d += hs[c] * att_dst[c]; }
    *(float4*)(npack + (size_t)i * 8)     = make_float4(hs[0], hs[1], hs[2], hs[3]);
    *(float4*)(npack + (size_t)i * 8 + 4) = make_float4(hs[4], a_s, a_d, 0.f);
}

__global__ __launch_bounds__(256) void k_edge_fb(
    const int* __restrict__ ei, const float* __restrict__ ea,
    const float* __restrict__ We, const float* __restrict__ att_edge,
    const float* __restrict__ npack, float* __restrict__ acc,
    int* __restrict__ cnt, int nE)
{
    int e = blockIdx.x * 256 + threadIdx.x;
    if (e >= nE) return;
    float v0 = 0.f, v1 = 0.f;
#pragma unroll
    for (int c = 0; c < 5; ++c) { v0 += We[c] * att_edge[c]; v1 += We[5 + c] * att_edge[c]; }
    int s = ei[e];
    int d = ei[nE + e];
    float2 at = *(const float2*)(ea + (size_t)e * 2);
    const float4 p0 = *(const float4*)(npack + (size_t)s * 8);
    const float2 p1 = *(const float2*)(npack + (size_t)s * 8 + 4);
    float a_dst_d = npack[(size_t)d * 8 + 6];
    float z = p1.y + a_dst_d + (at.x * v0 + at.y * v1);
    float l = z > 0.f ? z : NEG_SLOPE * z;
    float ev = __expf(l);
    float* ad = acc + (size_t)d * 8;
    unsafeAtomicAdd(ad + 0, ev * p0.x);
    unsafeAtomicAdd(ad + 1, ev * p0.y);
    unsafeAtomicAdd(ad + 2, ev * p0.z);
    unsafeAtomicAdd(ad + 3, ev * p0.w);
    unsafeAtomicAdd(ad + 4, ev * p1.x);
    unsafeAtomicAdd(ad + 5, ev);
    int cb = (at.x < CONSUME_R ? 1 : 0) | (at.y == 1.0f ? (1 << 16) : 0);
    if (cb) atomicAdd(cnt + s, cb);
}

__global__ __launch_bounds__(256) void k_final_fb(
    const float* __restrict__ x, const float* __restrict__ acc,
    const int* __restrict__ cnt,
    const float* __restrict__ gat_bias, const float* __restrict__ W1,
    const float* __restrict__ b1, const float* __restrict__ W2,
    const float* __restrict__ b2,
    float* __restrict__ out, float* __restrict__ scal, int n)
{
    int i = blockIdx.x * 256 + threadIdx.x;
    float part[5] = {0.f, 0.f, 0.f, 0.f, 0.f};
    if (i < n) {
        const float* a = acc + (size_t)i * 8;
        float inv = 1.0f / fmaxf(a[5], 1e-16f);
        float h[5];
#pragma unroll
        for (int c = 0; c < 5; ++c) h[c] = a[c] * inv + gat_bias[c];
        float tt[5];
#pragma unroll
        for (int c = 0; c < 5; ++c) {
            float s = b1[c];
#pragma unroll
            for (int k = 0; k < 5; ++k) s += h[k] * W1[k * 5 + c];
            tt[c] = fmaxf(s, 0.f);
        }
        float u0 = b2[0], u1 = b2[1];
#pragma unroll
        for (int k = 0; k < 5; ++k) { u0 += tt[k] * W2[k * 2]; u1 += tt[k] * W2[k * 2 + 1]; }
        u0 = fmaxf(u0, 0.f) * 2.f - 1.f;
        u1 = fmaxf(u1, 0.f) * 2.f - 1.f;
        float px = x[(size_t)i * 5],     py = x[(size_t)i * 5 + 1];
        float vx = x[(size_t)i * 5 + 2], vy = x[(size_t)i * 5 + 3];
        float ty = x[(size_t)i * 5 + 4];
        float mask = (ty == 1.0f) ? 1.0f : 0.0f;
        float nvx = fminf(fmaxf(vx + u0 * ACCEL_SCALE * mask, -MAX_VEL), MAX_VEL);
        float nvy = fminf(fmaxf(vy + u1 * ACCEL_SCALE * mask, -MAX_VEL), MAX_VEL);
        float npx = px + nvx, npy = py + nvy;
        out[(size_t)i * 5]     = npx;
        out[(size_t)i * 5 + 1] = npy;
        out[(size_t)i * 5 + 2] = nvx;
        out[(size_t)i * 5 + 3] = nvy;
        out[(size_t)i * 5 + 4] = ty;
        part[0] = fabsf(nvx);
        part[1] = fabsf(nvy);
        float bc = 0.f;
        if (fabsf(npx) > 1.0f) bc += logf(fabsf(npx) + 1e-6f);
        if (fabsf(npy) > 1.0f) bc += logf(fabsf(npy) + 1e-6f);
        part[2] = bc;
        int c = cnt[i];
        part[3] = (ty == 0.0f && (c & 0xffff) >= 3) ? 1.f : 0.f;
        part[4] = (ty == 1.0f && (c >> 16) < 1) ? 1.f : 0.f;
    }
    __shared__ float sm[4][5];
#pragma unroll
    for (int q = 0; q < 5; ++q)
#pragma unroll
        for (int off = 32; off > 0; off >>= 1)
            part[q] += __shfl_down(part[q], off);
    int lane = threadIdx.x & 63, wid = threadIdx.x >> 6;
    if (lane == 0)
#pragma unroll
        for (int q = 0; q < 5; ++q) sm[wid][q] = part[q];
    __syncthreads();
    if (threadIdx.x == 0) {
#pragma unroll
        for (int q = 0; q < 5; ++q)
            unsafeAtomicAdd(scal + q, sm[0][q] + sm[1][q] + sm[2][q] + sm[3][q]);
    }
}

// ---------------------------------------------------------------------------
extern "C" void kernel_launch(void* const* d_in, const int* in_sizes, int n_in,
                              void* d_out, int out_size, void* d_ws, size_t ws_size,
                              hipStream_t stream)
{
    const float* x        = (const float*)d_in[0];
    const int*   ei       = (const int*)  d_in[1];
    const float* ea       = (const float*)d_in[2];
    const float* W        = (const float*)d_in[3];
    const float* att_src  = (const float*)d_in[4];
    const float* att_dst  = (const float*)d_in[5];
    const float* We       = (const float*)d_in[6];
    const float* att_edge = (const float*)d_in[7];
    const float* gat_bias = (const float*)d_in[8];
    const float* W1       = (const float*)d_in[9];
    const float* b1       = (const float*)d_in[10];
    const float* W2       = (const float*)d_in[11];
    const float* b2       = (const float*)d_in[12];

    int n  = in_sizes[0] / 5;
    int nE = in_sizes[1] / 2;

    int npb = (n + NBUCK - 1) / NBUCK;
    int NB = (nE + EPB - 1) / EPB;
    int G = GSPLIT;
    int SPG = (NB + G - 1) / G;
    float inv_npb = 1.0f / (float)npb;

    size_t o = 0;
    auto alloc = [&](size_t bytes) { size_t r = o; o = (o + bytes + 63) & ~63ULL; return r; };
    size_t off_npack = alloc((size_t)n * 16);
    size_t off_aD    = alloc((size_t)n * 4);
    size_t off_hist  = alloc((size_t)NBUCK * NB * 4);
    size_t off_rtot  = alloc((size_t)NBUCK * 4);
    size_t off_bbase = alloc((size_t)(NBUCK + 1) * 4);
    size_t off_dirS  = alloc((size_t)(NBUCK + 1) * NB * 4);
    size_t off_accp  = alloc((size_t)NBUCK * G * npb * 24);
    size_t off_cntp  = alloc((size_t)NBUCK * G * npb * 4);
    size_t off_payS  = alloc((size_t)NB * EPB * 2);
    size_t off_scal  = alloc(64);
    size_t off_payD  = alloc(0);  // payload goes last (size depends on variant)
    size_t need8  = off_payD + (size_t)nE * 8;
    size_t need16 = off_payD + (size_t)nE * 16;

    char* wsb = (char*)d_ws;
    bool ok_shape = (n < (1 << 18)) && (npb <= MAXNPB) && (SPG <= MAXSPG) && (NB >= 1);
    int mode = (!ok_shape) ? 0 : (ws_size >= need16 ? 2 : (ws_size >= need8 ? 1 : 0));

    if (mode > 0) {
        uint4*          npack = (uint4*)(wsb + off_npack);
        float*          aD    = (float*)(wsb + off_aD);
        int*            hist  = (int*)(wsb + off_hist);
        int*            rtot  = (int*)(wsb + off_rtot);
        int*            bbase = (int*)(wsb + off_bbase);
        int*            dirS  = (int*)(wsb + off_dirS);
        float*          accp  = (float*)(wsb + off_accp);
        int*            cntp  = (int*)(wsb + off_cntp);
        unsigned short* payS  = (unsigned short*)(wsb + off_payS);
        float*          scal  = (float*)(wsb + off_scal);
        void*           payD  = (void*)(wsb + off_payD);

        hipMemsetAsync(scal, 0, 64, stream);
        k_pre<<<(n + 255) / 256, 256, 0, stream>>>(x, W, att_src, att_dst, npack, aD, n);
        k_hist<<<NB, TPB, 0, stream>>>(ei + nE, hist, NB, nE, (unsigned)npb, inv_npb);
        k_scanA<<<NBUCK, 256, 0, stream>>>(hist, rtot, NB);
        k_scanB<<<1, 128, 0, stream>>>(rtot, bbase);
        if (mode == 2) {
            k_scatter<true><<<NB, TPB, 0, stream>>>(ei, ea, npack, We, att_edge,
                hist, bbase, payD, payS, dirS, NB, nE, (unsigned)npb, inv_npb);
            k_accum<true><<<NBUCK * G, 1024, 0, stream>>>(payD, payS, bbase, dirS,
                npack, aD, accp, cntp, NB, G, SPG, n, npb);
        } else {
            k_scatter<false><<<NB, TPB, 0, stream>>>(ei, ea, npack, We, att_edge,
                hist, bbase, payD, payS, dirS, NB, nE, (unsigned)npb, inv_npb);
            k_accum<false><<<NBUCK * G, 1024, 0, stream>>>(payD, payS, bbase, dirS,
                npack, aD, accp, cntp, NB, G, SPG, n, npb);
        }
        k_final<<<(n + 255) / 256, 256, 0, stream>>>(x, accp, cntp, G, npb, inv_npb,
            gat_bias, W1, b1, W2, b2, (float*)d_out, scal, n);
        k_tail<<<1, 64, 0, stream>>>(scal, (float*)d_out, n);
    } else {
        float* ws    = (float*)d_ws;
        float* npk   = ws;
        float* acc   = ws + (size_t)n * 8;
        int*   cnt   = (int*)(acc + (size_t)n * 8);
        float* scal  = (float*)(cnt + n);
        size_t zbytes = ((size_t)n * 8 + (size_t)n + 8) * sizeof(float);
        hipMemsetAsync(acc, 0, zbytes, stream);
        k_node_pre_fb<<<(n + 255) / 256, 256, 0, stream>>>(x, W, att_src, att_dst, npk, n);
        k_edge_fb<<<(nE + 255) / 256, 256, 0, stream>>>(ei, ea, We, att_edge, npk,
                                                        acc, cnt, nE);
        k_final_fb<<<(n + 255) / 256, 256, 0, stream>>>(x, acc, cnt, gat_bias, W1, b1,
                                                        W2, b2, (float*)d_out, scal, n);
        k_tail<<<1, 64, 0, stream>>>(scal, (float*)d_out, n);
    }
}

// Round 7
// 699.563 us; speedup vs baseline: 1.2508x; 1.2508x over previous
//
#include <hip/hip_runtime.h>
#include <math.h>

#define NEG_SLOPE   0.2f
#define CONSUME_R   0.1f     // RADIUS*2
#define ACCEL_SCALE 0.01f
#define MAX_VEL     0.1f

#define NBUCK  2048
#define TPB    512
#define EPT    16
#define EPB    (TPB*EPT)     // 8192 edges per slice
#define MAXNPB 128
#define SMAX   6912          // max bucket span held in LDS (mean 6250 at 12.8M edges)

typedef float    v2f __attribute__((ext_vector_type(2)));
typedef unsigned v2u __attribute__((ext_vector_type(2)));

__device__ __forceinline__ unsigned bucket_of(unsigned v, unsigned npb, float inv_npb,
                                              unsigned* loc)
{
    unsigned b = (unsigned)((float)v * inv_npb);
    unsigned lo = b * npb;
    if (v < lo)            { --b; lo -= npb; }
    else if (v >= lo + npb){ ++b; lo += npb; }
    *loc = v - lo;
    return b;
}

// ---------------------------------------------------------------------------
// k_pre: npack[i] = {h0|h1, h2|h3, h4, aS} (h bf16), aD[i] fp32
// ---------------------------------------------------------------------------
__global__ __launch_bounds__(256) void k_pre(
    const float* __restrict__ x, const float* __restrict__ W,
    const float* __restrict__ att_src, const float* __restrict__ att_dst,
    uint4* __restrict__ npack, float* __restrict__ aD, int n)
{
    int i = blockIdx.x * 256 + threadIdx.x;
    if (i >= n) return;
    float xr[5];
#pragma unroll
    for (int k = 0; k < 5; ++k) xr[k] = x[(size_t)i * 5 + k];
    float hs[5];
#pragma unroll
    for (int c = 0; c < 5; ++c) {
        float s = 0.f;
#pragma unroll
        for (int k = 0; k < 5; ++k) s += xr[k] * W[k * 5 + c];
        hs[c] = s;
    }
    float a_s = 0.f, a_d = 0.f;
#pragma unroll
    for (int c = 0; c < 5; ++c) { a_s += hs[c] * att_src[c]; a_d += hs[c] * att_dst[c]; }
    aD[i] = a_d;
    unsigned b[5];
#pragma unroll
    for (int c = 0; c < 5; ++c) {   // round-to-nearest-even bf16
        unsigned u = __float_as_uint(hs[c]);
        b[c] = (u + 0x7FFFu + ((u >> 16) & 1u)) >> 16;
    }
    npack[i] = make_uint4(b[0] | (b[1] << 16), b[2] | (b[3] << 16), b[4],
                          __float_as_uint(a_s));
}

// ---------------------------------------------------------------------------
// k_hist: per-slice dst-bucket histogram. hist layout [slice][bucket].
// ---------------------------------------------------------------------------
__global__ __launch_bounds__(TPB) void k_hist(
    const int* __restrict__ dst, int* __restrict__ hist,
    int NB, int nE, unsigned npb, float inv_npb)
{
    __shared__ int hd[NBUCK];
    int t = threadIdx.x, blk = blockIdx.x;
    for (int j = t; j < NBUCK; j += TPB) hd[j] = 0;
    __syncthreads();
    int base = blk * EPB;
#pragma unroll 4
    for (int k = 0; k < EPT; ++k) {
        int e = base + k * TPB + t;
        if (e < nE) {
            unsigned loc;
            unsigned bd = bucket_of((unsigned)__builtin_nontemporal_load(dst + e),
                                    npb, inv_npb, &loc);
            atomicAdd(&hd[bd], 1);
        }
    }
    __syncthreads();
    for (int j = t; j < NBUCK; j += TPB) hist[(size_t)blk * NBUCK + j] = hd[j];
}

// ---------------------------------------------------------------------------
// k_scanA: exclusive scan of each bucket COLUMN (strided) over slices.
// ---------------------------------------------------------------------------
__global__ __launch_bounds__(256) void k_scanA(
    int* __restrict__ hist, int* __restrict__ rowtot, int NB)
{
    int b = blockIdx.x, t = threadIdx.x;
    __shared__ int ws4[4];
    __shared__ int carry;
    if (t == 0) carry = 0;
    __syncthreads();
    for (int base = 0; base < NB; base += 256) {
        int i = base + t;
        int v = (i < NB) ? hist[(size_t)i * NBUCK + b] : 0;
        int xv = v;
#pragma unroll
        for (int off = 1; off < 64; off <<= 1) {
            int y = __shfl_up(xv, off);
            if ((t & 63) >= off) xv += y;
        }
        if ((t & 63) == 63) ws4[t >> 6] = xv;
        __syncthreads();
        int add = 0;
        for (int w = 0; w < (t >> 6); ++w) add += ws4[w];
        int total = ws4[0] + ws4[1] + ws4[2] + ws4[3];
        if (i < NB) hist[(size_t)i * NBUCK + b] = carry + xv + add - v;
        __syncthreads();
        if (t == 0) carry += total;
        __syncthreads();
    }
    if (t == 0) rowtot[b] = carry;
}

// k_scanB: exclusive scan of rowtot[NBUCK] -> bbase[0..NBUCK]. 1024 thr, 2/thr.
__global__ __launch_bounds__(1024) void k_scanB(
    const int* __restrict__ rowtot, int* __restrict__ bbase)
{
    __shared__ int wsum[16], wex[16];
    int t = threadIdx.x;
    int a = rowtot[2 * t], b2 = rowtot[2 * t + 1];
    int v = a + b2;
    int xv = v;
#pragma unroll
    for (int off = 1; off < 64; off <<= 1) {
        int y = __shfl_up(xv, off);
        if ((t & 63) >= off) xv += y;
    }
    if ((t & 63) == 63) wsum[t >> 6] = xv;
    __syncthreads();
    if (t == 0) { int r = 0; for (int w = 0; w < 16; ++w) { wex[w] = r; r += wsum[w]; } }
    __syncthreads();
    int excl = xv - v + wex[t >> 6];
    bbase[2 * t] = excl;
    bbase[2 * t + 1] = excl + a;
    if (t == 1023) bbase[NBUCK] = excl + v;
}

// ---------------------------------------------------------------------------
// k_scatter: one edge pass, no node gathers. Rec = {src|dloc<<18, a_e f32},
// written bucket-contiguous (base = bbase[bd] + hist[slice][bd], LDS rank).
// payS (src-keyed flags) slice-local in LDS, dumped contiguously.
// dirS[slice][bucket] = base | count<<16 (slice-local).
// ---------------------------------------------------------------------------
__global__ __launch_bounds__(TPB) void k_scatter(
    const int* __restrict__ ei, const float* __restrict__ ea,
    const float* __restrict__ We, const float* __restrict__ att_edge,
    const int* __restrict__ hist, const int* __restrict__ bbase,
    unsigned* __restrict__ payD, unsigned short* __restrict__ payS,
    int* __restrict__ dirS, int NB, int nE, unsigned npb, float inv_npb)
{
    __shared__ int cD[NBUCK], cS[NBUCK], baseS[NBUCK], dirGl[NBUCK];
    __shared__ unsigned short paySL[EPB];
    __shared__ int wsc[8], wex[8];
    int t = threadIdx.x, blk = blockIdx.x;
    for (int j = t; j < NBUCK; j += TPB) {
        cD[j] = 0; cS[j] = 0;
        dirGl[j] = bbase[j] + hist[(size_t)blk * NBUCK + j];
    }
    __syncthreads();

    float v0 = 0.f, v1 = 0.f;
#pragma unroll
    for (int c = 0; c < 5; ++c) { v0 += We[c] * att_edge[c]; v1 += We[5 + c] * att_edge[c]; }

    int base = blk * EPB;
    unsigned key[EPT], bb[EPT];
    float ae[EPT];

    // pass A: stream edges, compute buckets, count cS (flagged only)
#pragma unroll
    for (int k = 0; k < EPT; ++k) {
        int e = base + k * TPB + t;
        bb[k] = 0;
        if (e < nE) {
            unsigned s = (unsigned)__builtin_nontemporal_load(ei + e);
            unsigned d = (unsigned)__builtin_nontemporal_load(ei + nE + e);
            v2f at = __builtin_nontemporal_load((const v2f*)ea + e);
            unsigned dloc, sloc;
            unsigned bd = bucket_of(d, npb, inv_npb, &dloc);
            unsigned bs = bucket_of(s, npb, inv_npb, &sloc);
            ae[k]  = at.x * v0 + at.y * v1;
            key[k] = s | (dloc << 18);
            bool close = at.x < CONSUME_R;
            bool cell  = (at.y == 1.0f);
            bb[k] = bd | (bs << 11) | (close ? (1u << 22) : 0u)
                       | (cell ? (1u << 23) : 0u) | (1u << 24);
            if (close || cell) atomicAdd(&cS[bs], 1);
        }
    }
    __syncthreads();

    // block-wide exclusive scan of cS[2048] (4 per thread)
    {
        int a0 = cS[4 * t], a1 = cS[4 * t + 1], a2 = cS[4 * t + 2], a3 = cS[4 * t + 3];
        int lsum = a0 + a1 + a2 + a3;
        int xv = lsum;
#pragma unroll
        for (int off = 1; off < 64; off <<= 1) {
            int y = __shfl_up(xv, off);
            if ((t & 63) >= off) xv += y;
        }
        if ((t & 63) == 63) wsc[t >> 6] = xv;
        __syncthreads();
        if (t == 0) { int r = 0; for (int w = 0; w < 8; ++w) { wex[w] = r; r += wsc[w]; } }
        __syncthreads();
        int b0 = xv - lsum + wex[t >> 6];
        baseS[4 * t]     = b0;
        baseS[4 * t + 1] = b0 + a0;
        baseS[4 * t + 2] = b0 + a0 + a1;
        baseS[4 * t + 3] = b0 + a0 + a1 + a2;
    }
    __syncthreads();
    // dirS packed (base | count<<16); reset cS to use as rank cursor
    for (int j = t; j < NBUCK; j += TPB) {
        dirS[(size_t)blk * NBUCK + j] = baseS[j] | (cS[j] << 16);
        cS[j] = 0;
    }
    __syncthreads();

    // pass B: rank + write payD (global bucket runs) and payS (LDS)
#pragma unroll
    for (int k = 0; k < EPT; ++k) {
        if (bb[k] & (1u << 24)) {
            unsigned bd = bb[k] & 0x7FFu;
            int r = atomicAdd(&cD[bd], 1);
            v2u rec; rec.x = key[k]; rec.y = __float_as_uint(ae[k]);
            ((v2u*)payD)[dirGl[bd] + r] = rec;
            if (bb[k] & 0xC00000u) {
                unsigned bs = (bb[k] >> 11) & 0x7FFu;
                unsigned sloc = (key[k] & 0x3FFFFu) - bs * npb;
                unsigned srec = sloc | ((bb[k] >> 22) & 1u) << 11 | ((bb[k] >> 23) & 1u) << 12;
                int r2 = atomicAdd(&cS[bs], 1);
                paySL[baseS[bs] + r2] = (unsigned short)srec;
            }
        }
    }
    __syncthreads();

    // dump payS slice contiguously (16 KB)
    unsigned* pgs = (unsigned*)(payS + (size_t)blk * EPB);
    const unsigned* pls = (const unsigned*)paySL;
#pragma unroll
    for (int j = 0; j < EPB / 2 / TPB; ++j) pgs[j * TPB + t] = pls[j * TPB + t];
}

// ---------------------------------------------------------------------------
// k_sortred: per bucket. Counting-sort the bucket span into LDS, then
// ATOMIC-FREE per-node segmented reduction; fused MLP/physics/finalize.
// ---------------------------------------------------------------------------
__global__ __launch_bounds__(1024) void k_sortred(
    const unsigned* __restrict__ payD, const unsigned short* __restrict__ payS,
    const int* __restrict__ bbase, const int* __restrict__ dirS,
    const uint4* __restrict__ npack, const float* __restrict__ aD,
    const float* __restrict__ x,
    const float* __restrict__ gat_bias, const float* __restrict__ W1,
    const float* __restrict__ b1, const float* __restrict__ W2,
    const float* __restrict__ b2,
    float* __restrict__ out, float* __restrict__ scal,
    int NB, int n, int npb)
{
    __shared__ unsigned srt[SMAX * 2];          // 55.3 KB sorted recs
    __shared__ float accf[MAXNPB * 6];
    __shared__ float aDl[MAXNPB];
    __shared__ int cntL[MAXNPB], offL[MAXNPB], cnts[MAXNPB];
    __shared__ float sm[16][5];

    int b = blockIdx.x, t = threadIdx.x;
    int lo = bbase[b], hi = bbase[b + 1], span = hi - lo;
    int first = b * npb;
    int nodes = n - first; if (nodes > npb) nodes = npb; if (nodes < 0) nodes = 0;

    for (int j = t; j < npb; j += 1024) { cntL[j] = 0; cnts[j] = 0; }
    for (int j = t; j < npb * 6; j += 1024) accf[j] = 0.f;
    for (int j = t; j < nodes; j += 1024) aDl[j] = aD[first + j];
    __syncthreads();

    int grp = t >> 4, l16 = t & 15;   // 64 groups of 16 lanes

    if (span <= SMAX) {
        // pass 1: count per dloc
        for (int idx = lo + t; idx < hi; idx += 1024) {
            unsigned w0 = __builtin_nontemporal_load(payD + 2 * (size_t)idx);
            atomicAdd(&cntL[(w0 >> 18) & 0x3FFu], 1);
        }
        __syncthreads();
        if (t == 0) {
            int r = 0;
            for (int j = 0; j < nodes; ++j) { offL[j] = r; r += cntL[j]; cntL[j] = 0; }
        }
        __syncthreads();
        // pass 2: rank + place into LDS (span is L2-hot from pass 1)
        for (int idx = lo + t; idx < hi; idx += 1024) {
            v2u rec = *((const v2u*)payD + idx);
            unsigned dl = (rec.x >> 18) & 0x3FFu;
            int r = atomicAdd(&cntL[dl], 1);
            int p = offL[dl] + r;
            srt[2 * p] = rec.x; srt[2 * p + 1] = rec.y;
        }
        __syncthreads();
        // pass 3: segmented reduce, one node per 16-lane group (atomic-free)
        for (int nd = grp; nd < nodes; nd += 64) {
            int s = offL[nd], e = s + cntL[nd];
            float s0 = 0.f, s1 = 0.f, s2 = 0.f, s3 = 0.f, s4 = 0.f, s5 = 0.f;
            for (int j = s + l16; j < e; j += 16) {
                unsigned w0 = srt[2 * j];
                float aev = __uint_as_float(srt[2 * j + 1]);
                uint4 hp = npack[w0 & 0x3FFFFu];
                float z = __uint_as_float(hp.w) + aev + aDl[nd];
                float l = z > 0.f ? z : NEG_SLOPE * z;
                float ev = __expf(l);
                s0 += ev * __uint_as_float(hp.x << 16);
                s1 += ev * __uint_as_float(hp.x & 0xFFFF0000u);
                s2 += ev * __uint_as_float(hp.y << 16);
                s3 += ev * __uint_as_float(hp.y & 0xFFFF0000u);
                s4 += ev * __uint_as_float(hp.z << 16);
                s5 += ev;
            }
#pragma unroll
            for (int m = 1; m < 16; m <<= 1) {
                s0 += __shfl_xor(s0, m);
                s1 += __shfl_xor(s1, m);
                s2 += __shfl_xor(s2, m);
                s3 += __shfl_xor(s3, m);
                s4 += __shfl_xor(s4, m);
                s5 += __shfl_xor(s5, m);
            }
            if (l16 == 0) {
                float* a = &accf[nd * 6];
                a[0] += s0; a[1] += s1; a[2] += s2; a[3] += s3; a[4] += s4; a[5] += s5;
            }
        }
    } else {
        // overflow fallback (not expected): direct atomic accumulate
        for (int idx = lo + t; idx < hi; idx += 1024) {
            v2u rec = *((const v2u*)payD + idx);
            unsigned dl = (rec.x >> 18) & 0x3FFu;
            uint4 hp = npack[rec.x & 0x3FFFFu];
            float z = __uint_as_float(hp.w) + __uint_as_float(rec.y) + aDl[dl];
            float l = z > 0.f ? z : NEG_SLOPE * z;
            float ev = __expf(l);
            float* a = &accf[dl * 6];
            atomicAdd(a + 0, ev * __uint_as_float(hp.x << 16));
            atomicAdd(a + 1, ev * __uint_as_float(hp.x & 0xFFFF0000u));
            atomicAdd(a + 2, ev * __uint_as_float(hp.y << 16));
            atomicAdd(a + 3, ev * __uint_as_float(hp.y & 0xFFFF0000u));
            atomicAdd(a + 4, ev * __uint_as_float(hp.z << 16));
            atomicAdd(a + 5, ev);
        }
    }

    // payS walk: per-slice runs for this bucket (src-keyed close/cell counts)
    for (int s = grp; s < NB; s += 64) {
        int pk = dirS[(size_t)s * NBUCK + b];
        int st = pk & 0xFFFF, cn = ((unsigned)pk) >> 16;
        size_t sb = (size_t)s * EPB;
        for (int j = st + l16; j < st + cn; j += 16) {
            unsigned sr = payS[sb + j];
            int add = (int)((sr >> 11) & 1u) | (int)(((sr >> 12) & 1u) << 16);
            atomicAdd(&cnts[sr & 0x3FFu], add);
        }
    }
    __syncthreads();

    // fused finalize
    float part[5] = {0.f, 0.f, 0.f, 0.f, 0.f};
    if (t < nodes) {
        int i = first + t;
        const float* a = &accf[t * 6];
        float inv = 1.0f / fmaxf(a[5], 1e-16f);
        float h[5];
#pragma unroll
        for (int c = 0; c < 5; ++c) h[c] = a[c] * inv + gat_bias[c];
        float tt[5];
#pragma unroll
        for (int c = 0; c < 5; ++c) {
            float s = b1[c];
#pragma unroll
            for (int k = 0; k < 5; ++k) s += h[k] * W1[k * 5 + c];
            tt[c] = fmaxf(s, 0.f);
        }
        float u0 = b2[0], u1 = b2[1];
#pragma unroll
        for (int k = 0; k < 5; ++k) { u0 += tt[k] * W2[k * 2]; u1 += tt[k] * W2[k * 2 + 1]; }
        u0 = fmaxf(u0, 0.f) * 2.f - 1.f;
        u1 = fmaxf(u1, 0.f) * 2.f - 1.f;

        float px = x[(size_t)i * 5],     py = x[(size_t)i * 5 + 1];
        float vx = x[(size_t)i * 5 + 2], vy = x[(size_t)i * 5 + 3];
        float ty = x[(size_t)i * 5 + 4];
        float mask = (ty == 1.0f) ? 1.0f : 0.0f;
        float nvx = fminf(fmaxf(vx + u0 * ACCEL_SCALE * mask, -MAX_VEL), MAX_VEL);
        float nvy = fminf(fmaxf(vy + u1 * ACCEL_SCALE * mask, -MAX_VEL), MAX_VEL);
        float npx = px + nvx, npy = py + nvy;

        out[(size_t)i * 5]     = npx;
        out[(size_t)i * 5 + 1] = npy;
        out[(size_t)i * 5 + 2] = nvx;
        out[(size_t)i * 5 + 3] = nvy;
        out[(size_t)i * 5 + 4] = ty;

        part[0] = fabsf(nvx);
        part[1] = fabsf(nvy);
        float bc = 0.f;
        if (fabsf(npx) > 1.0f) bc += logf(fabsf(npx) + 1e-6f);
        if (fabsf(npy) > 1.0f) bc += logf(fabsf(npy) + 1e-6f);
        part[2] = bc;
        int c = cnts[t];
        part[3] = (ty == 0.0f && (c & 0xffff) >= 3) ? 1.f : 0.f;
        part[4] = (ty == 1.0f && (c >> 16) < 1) ? 1.f : 0.f;
    }

#pragma unroll
    for (int q = 0; q < 5; ++q)
#pragma unroll
        for (int off = 32; off > 0; off >>= 1)
            part[q] += __shfl_down(part[q], off);
    int lane = t & 63, wid = t >> 6;
    if (lane == 0)
#pragma unroll
        for (int q = 0; q < 5; ++q) sm[wid][q] = part[q];
    __syncthreads();
    if (t == 0) {
#pragma unroll
        for (int q = 0; q < 5; ++q) {
            float s = 0.f;
#pragma unroll
            for (int w = 0; w < 16; ++w) s += sm[w][q];
            unsafeAtomicAdd(scal + q, s);
        }
    }
}

__global__ void k_tail(const float* __restrict__ scal, float* __restrict__ out, int n)
{
    if (threadIdx.x == 0 && blockIdx.x == 0) {
        size_t base = (size_t)n * 5;
        float invn = 1.0f / (float)n;
        out[base + 0] = scal[0] * invn;
        out[base + 1] = scal[1] * invn;
        out[base + 2] = scal[2];
        out[base + 3] = scal[3];
        out[base + 4] = scal[4];
    }
}

// ------------------- fallback (round-1 atomic path) ------------------------
__global__ __launch_bounds__(256) void k_node_pre_fb(
    const float* __restrict__ x, const float* __restrict__ W,
    const float* __restrict__ att_src, const float* __restrict__ att_dst,
    float* __restrict__ npack, int n)
{
    int i = blockIdx.x * 256 + threadIdx.x;
    if (i >= n) return;
    float xr[5];
#pragma unroll
    for (int k = 0; k < 5; ++k) xr[k] = x[(size_t)i * 5 + k];
    float hs[5];
#pragma unroll
    for (int c = 0; c < 5; ++c) {
        float s = 0.f;
#pragma unroll
        for (int k = 0; k < 5; ++k) s += xr[k] * W[k * 5 + c];
        hs[c] = s;
    }
    float a_s = 0.f, a_d = 0.f;
#pragma unroll
    for (int c = 0; c < 5; ++c) { a_s += hs[c] * att_src[c]; a_d += hs[c] * att_dst[c]; }
    *(float4*)(npack + (size_t)i * 8)     = make_float4(hs[0], hs[1], hs[2], hs[3]);
    *(float4*)(npack + (size_t)i * 8 + 4) = make_float4(hs[4], a_s, a_d, 0.f);
}

__global__ __launch_bounds__(256) void k_edge_fb(
    const int* __restrict__ ei, const float* __restrict__ ea,
    const float* __restrict__ We, const float* __restrict__ att_edge,
    const float* __restrict__ npack, float* __restrict__ acc,
    int* __restrict__ cnt, int nE)
{
    int e = blockIdx.x * 256 + threadIdx.x;
    if (e >= nE) return;
    float v0 = 0.f, v1 = 0.f;
#pragma unroll
    for (int c = 0; c < 5; ++c) { v0 += We[c] * att_edge[c]; v1 += We[5 + c] * att_edge[c]; }
    int s = ei[e];
    int d = ei[nE + e];
    float2 at = *(const float2*)(ea + (size_t)e * 2);
    const float4 p0 = *(const float4*)(npack + (size_t)s * 8);
    const float2 p1 = *(const float2*)(npack + (size_t)s * 8 + 4);
    float a_dst_d = npack[(size_t)d * 8 + 6];
    float z = p1.y + a_dst_d + (at.x * v0 + at.y * v1);
    float l = z > 0.f ? z : NEG_SLOPE * z;
    float ev = __expf(l);
    float* ad = acc + (size_t)d * 8;
    unsafeAtomicAdd(ad + 0, ev * p0.x);
    unsafeAtomicAdd(ad + 1, ev * p0.y);
    unsafeAtomicAdd(ad + 2, ev * p0.z);
    unsafeAtomicAdd(ad + 3, ev * p0.w);
    unsafeAtomicAdd(ad + 4, ev * p1.x);
    unsafeAtomicAdd(ad + 5, ev);
    int cb = (at.x < CONSUME_R ? 1 : 0) | (at.y == 1.0f ? (1 << 16) : 0);
    if (cb) atomicAdd(cnt + s, cb);
}

__global__ __launch_bounds__(256) void k_final_fb(
    const float* __restrict__ x, const float* __restrict__ acc,
    const int* __restrict__ cnt,
    const float* __restrict__ gat_bias, const float* __restrict__ W1,
    const float* __restrict__ b1, const float* __restrict__ W2,
    const float* __restrict__ b2,
    float* __restrict__ out, float* __restrict__ scal, int n)
{
    int i = blockIdx.x * 256 + threadIdx.x;
    float part[5] = {0.f, 0.f, 0.f, 0.f, 0.f};
    if (i < n) {
        const float* a = acc + (size_t)i * 8;
        float inv = 1.0f / fmaxf(a[5], 1e-16f);
        float h[5];
#pragma unroll
        for (int c = 0; c < 5; ++c) h[c] = a[c] * inv + gat_bias[c];
        float tt[5];
#pragma unroll
        for (int c = 0; c < 5; ++c) {
            float s = b1[c];
#pragma unroll
            for (int k = 0; k < 5; ++k) s += h[k] * W1[k * 5 + c];
            tt[c] = fmaxf(s, 0.f);
        }
        float u0 = b2[0], u1 = b2[1];
#pragma unroll
        for (int k = 0; k < 5; ++k) { u0 += tt[k] * W2[k * 2]; u1 += tt[k] * W2[k * 2 + 1]; }
        u0 = fmaxf(u0, 0.f) * 2.f - 1.f;
        u1 = fmaxf(u1, 0.f) * 2.f - 1.f;
        float px = x[(size_t)i * 5],     py = x[(size_t)i * 5 + 1];
        float vx = x[(size_t)i * 5 + 2], vy = x[(size_t)i * 5 + 3];
        float ty = x[(size_t)i * 5 + 4];
        float mask = (ty == 1.0f) ? 1.0f : 0.0f;
        float nvx = fminf(fmaxf(vx + u0 * ACCEL_SCALE * mask, -MAX_VEL), MAX_VEL);
        float nvy = fminf(fmaxf(vy + u1 * ACCEL_SCALE * mask, -MAX_VEL), MAX_VEL);
        float npx = px + nvx, npy = py + nvy;
        out[(size_t)i * 5]     = npx;
        out[(size_t)i * 5 + 1] = npy;
        out[(size_t)i * 5 + 2] = nvx;
        out[(size_t)i * 5 + 3] = nvy;
        out[(size_t)i * 5 + 4] = ty;
        part[0] = fabsf(nvx);
        part[1] = fabsf(nvy);
        float bc = 0.f;
        if (fabsf(npx) > 1.0f) bc += logf(fabsf(npx) + 1e-6f);
        if (fabsf(npy) > 1.0f) bc += logf(fabsf(npy) + 1e-6f);
        part[2] = bc;
        int c = cnt[i];
        part[3] = (ty == 0.0f && (c & 0xffff) >= 3) ? 1.f : 0.f;
        part[4] = (ty == 1.0f && (c >> 16) < 1) ? 1.f : 0.f;
    }
    __shared__ float sm[4][5];
#pragma unroll
    for (int q = 0; q < 5; ++q)
#pragma unroll
        for (int off = 32; off > 0; off >>= 1)
            part[q] += __shfl_down(part[q], off);
    int lane = threadIdx.x & 63, wid = threadIdx.x >> 6;
    if (lane == 0)
#pragma unroll
        for (int q = 0; q < 5; ++q) sm[wid][q] = part[q];
    __syncthreads();
    if (threadIdx.x == 0) {
#pragma unroll
        for (int q = 0; q < 5; ++q)
            unsafeAtomicAdd(scal + q, sm[0][q] + sm[1][q] + sm[2][q] + sm[3][q]);
    }
}

// ---------------------------------------------------------------------------
extern "C" void kernel_launch(void* const* d_in, const int* in_sizes, int n_in,
                              void* d_out, int out_size, void* d_ws, size_t ws_size,
                              hipStream_t stream)
{
    const float* x        = (const float*)d_in[0];
    const int*   ei       = (const int*)  d_in[1];
    const float* ea       = (const float*)d_in[2];
    const float* W        = (const float*)d_in[3];
    const float* att_src  = (const float*)d_in[4];
    const float* att_dst  = (const float*)d_in[5];
    const float* We       = (const float*)d_in[6];
    const float* att_edge = (const float*)d_in[7];
    const float* gat_bias = (const float*)d_in[8];
    const float* b1       = (const float*)d_in[10];
    const float* W1       = (const float*)d_in[9];
    const float* W2       = (const float*)d_in[11];
    const float* b2       = (const float*)d_in[12];

    int n  = in_sizes[0] / 5;
    int nE = in_sizes[1] / 2;

    int npb = (n + NBUCK - 1) / NBUCK;
    int NB = (nE + EPB - 1) / EPB;
    float inv_npb = 1.0f / (float)npb;

    size_t o = 0;
    auto alloc = [&](size_t bytes) { size_t r = o; o = (o + bytes + 63) & ~63ULL; return r; };
    size_t off_npack = alloc((size_t)n * 16);
    size_t off_aD    = alloc((size_t)n * 4);
    size_t off_hist  = alloc((size_t)NB * NBUCK * 4);
    size_t off_rtot  = alloc((size_t)NBUCK * 4);
    size_t off_bbase = alloc((size_t)(NBUCK + 1) * 4);
    size_t off_dirS  = alloc((size_t)NB * NBUCK * 4);
    size_t off_payS  = alloc((size_t)NB * EPB * 2);
    size_t off_scal  = alloc(64);
    size_t off_payD  = alloc((size_t)nE * 8);
    size_t need = o;

    char* wsb = (char*)d_ws;
    bool ok_shape = (n < (1 << 18)) && (npb <= MAXNPB) && (NB >= 1);
    bool fast = ok_shape && (ws_size >= need);

    if (fast) {
        uint4*          npack = (uint4*)(wsb + off_npack);
        float*          aD    = (float*)(wsb + off_aD);
        int*            hist  = (int*)(wsb + off_hist);
        int*            rtot  = (int*)(wsb + off_rtot);
        int*            bbase = (int*)(wsb + off_bbase);
        int*            dirS  = (int*)(wsb + off_dirS);
        unsigned short* payS  = (unsigned short*)(wsb + off_payS);
        float*          scal  = (float*)(wsb + off_scal);
        unsigned*       payD  = (unsigned*)(wsb + off_payD);

        hipMemsetAsync(scal, 0, 64, stream);
        k_pre<<<(n + 255) / 256, 256, 0, stream>>>(x, W, att_src, att_dst, npack, aD, n);
        k_hist<<<NB, TPB, 0, stream>>>(ei + nE, hist, NB, nE, (unsigned)npb, inv_npb);
        k_scanA<<<NBUCK, 256, 0, stream>>>(hist, rtot, NB);
        k_scanB<<<1, 1024, 0, stream>>>(rtot, bbase);
        k_scatter<<<NB, TPB, 0, stream>>>(ei, ea, We, att_edge, hist, bbase,
                                          payD, payS, dirS, NB, nE, (unsigned)npb, inv_npb);
        k_sortred<<<NBUCK, 1024, 0, stream>>>(payD, payS, bbase, dirS, npack, aD, x,
                                              gat_bias, W1, b1, W2, b2,
                                              (float*)d_out, scal, NB, n, npb);
        k_tail<<<1, 64, 0, stream>>>(scal, (float*)d_out, n);
    } else {
        float* ws    = (float*)d_ws;
        float* npk   = ws;
        float* acc   = ws + (size_t)n * 8;
        int*   cnt   = (int*)(acc + (size_t)n * 8);
        float* scal  = (float*)(cnt + n);
        size_t zbytes = ((size_t)n * 8 + (size_t)n + 8) * sizeof(float);
        hipMemsetAsync(acc, 0, zbytes, stream);
        k_node_pre_fb<<<(n + 255) / 256, 256, 0, stream>>>(x, W, att_src, att_dst, npk, n);
        k_edge_fb<<<(nE + 255) / 256, 256, 0, stream>>>(ei, ea, We, att_edge, npk,
                                                        acc, cnt, nE);
        k_final_fb<<<(n + 255) / 256, 256, 0, stream>>>(x, acc, cnt, gat_bias, W1, b1,
                                                        W2, b2, (float*)d_out, scal, n);
        k_tail<<<1, 64, 0, stream>>>(scal, (float*)d_out, n);
    }
}